// Round 1
// baseline (5449.162 us; speedup 1.0000x reference)
//
#include <hip/hip_runtime.h>

#define NPTS 16384
#define DIM 256
#define KNN 5
#define QT 64     // query rows per block
#define CT 128    // candidate tile width
#define BK 32     // k-chunk staged in LDS

// LDS: staging buffers (k-major, padded) overlaid with the merge scratch.
struct StageMem { float As[BK][68]; float Bs[BK][132]; };           // 8704 + 16896 = 25600 B
struct MergeMem { float md[QT][16][KNN]; int mi[QT][16][KNN]; };    // 2 * 20480 = 40960 B
union ShMem { StageMem st; MergeMem mg; };

// Kernel 1: per-row squared norms + zero the match counter.
__global__ __launch_bounds__(256) void norms_init_kernel(const float* __restrict__ emb,
                                                         float* __restrict__ norms,
                                                         int* __restrict__ cnt) {
    if (blockIdx.x == 0 && threadIdx.x == 0) *cnt = 0;
    int row  = blockIdx.x * 4 + (threadIdx.x >> 6);
    int lane = threadIdx.x & 63;
    float4 v = *reinterpret_cast<const float4*>(emb + (size_t)row * DIM + lane * 4);
    float s = v.x * v.x + v.y * v.y + v.z * v.z + v.w * v.w;
#pragma unroll
    for (int off = 32; off > 0; off >>= 1) s += __shfl_down(s, off, 64);
    if (lane == 0) norms[row] = s;
}

// Kernel 2: fused distance GEMM + per-row top-5 (self excluded) + label match count.
__global__ __launch_bounds__(256, 3) void cmc_topk_kernel(const float* __restrict__ emb,
                                                          const int* __restrict__ labels,
                                                          const float* __restrict__ norms,
                                                          int* __restrict__ cnt) {
    __shared__ ShMem sh;
    const int tid = threadIdx.x;
    const int tx  = tid & 15;   // candidate group
    const int ty  = tid >> 4;   // query-row group (4 rows per thread)
    const int qbase = blockIdx.x * QT;

    // per-thread top-5 lists for 4 query rows, (dist, idx) lexicographic ascending
    float Ld[4][KNN];
    int   Li[4][KNN];
#pragma unroll
    for (int m = 0; m < 4; ++m)
#pragma unroll
        for (int e = 0; e < KNN; ++e) { Ld[m][e] = 3.0e38f; Li[m][e] = 0x7fffffff; }

    float sqA[4];
#pragma unroll
    for (int m = 0; m < 4; ++m) sqA[m] = norms[qbase + ty * 4 + m];

    for (int cb = 0; cb < NPTS; cb += CT) {
        float acc[4][8];
#pragma unroll
        for (int m = 0; m < 4; ++m)
#pragma unroll
            for (int n = 0; n < 8; ++n) acc[m][n] = 0.0f;

        for (int kb = 0; kb < DIM; kb += BK) {
            __syncthreads();  // previous chunk fully consumed before overwrite
            {
                const int kv = tid & 7;   // which float4 along k
                const int r0 = tid >> 3;  // 0..31
#pragma unroll
                for (int rr = 0; rr < 2; ++rr) {
                    int r = r0 + rr * 32;
                    float4 v = *reinterpret_cast<const float4*>(
                        emb + (size_t)(qbase + r) * DIM + kb + kv * 4);
                    sh.st.As[kv * 4 + 0][r] = v.x;
                    sh.st.As[kv * 4 + 1][r] = v.y;
                    sh.st.As[kv * 4 + 2][r] = v.z;
                    sh.st.As[kv * 4 + 3][r] = v.w;
                }
#pragma unroll
                for (int cc = 0; cc < 4; ++cc) {
                    int c = r0 + cc * 32;
                    float4 v = *reinterpret_cast<const float4*>(
                        emb + (size_t)(cb + c) * DIM + kb + kv * 4);
                    sh.st.Bs[kv * 4 + 0][c] = v.x;
                    sh.st.Bs[kv * 4 + 1][c] = v.y;
                    sh.st.Bs[kv * 4 + 2][c] = v.z;
                    sh.st.Bs[kv * 4 + 3][c] = v.w;
                }
            }
            __syncthreads();
#pragma unroll
            for (int k = 0; k < BK; ++k) {
                float4 av = *reinterpret_cast<const float4*>(&sh.st.As[k][ty * 4]);
                float4 b0 = *reinterpret_cast<const float4*>(&sh.st.Bs[k][tx * 4]);
                float4 b1 = *reinterpret_cast<const float4*>(&sh.st.Bs[k][64 + tx * 4]);
                float a[4] = {av.x, av.y, av.z, av.w};
                float b[8] = {b0.x, b0.y, b0.z, b0.w, b1.x, b1.y, b1.z, b1.w};
#pragma unroll
                for (int m = 0; m < 4; ++m)
#pragma unroll
                    for (int n = 0; n < 8; ++n)
                        acc[m][n] = fmaf(a[m], b[n], acc[m][n]);
            }
        }

        // finalize distances for this tile, update top-5 lists
        float sqB[8];
        int   cidx[8];
#pragma unroll
        for (int n = 0; n < 8; ++n) {
            int cl = (n < 4) ? (tx * 4 + n) : (64 + tx * 4 + (n - 4));
            cidx[n] = cb + cl;
            sqB[n]  = norms[cb + cl];
        }
#pragma unroll
        for (int m = 0; m < 4; ++m) {
            int q = qbase + ty * 4 + m;
#pragma unroll
            for (int n = 0; n < 8; ++n) {
                float dist = fmaf(-2.0f, acc[m][n], sqA[m] + sqB[n]);
                int   ci   = cidx[n];
                if (ci != q && (dist < Ld[m][KNN - 1] ||
                                (dist == Ld[m][KNN - 1] && ci < Li[m][KNN - 1]))) {
                    float cd = dist; int cc2 = ci;
#pragma unroll
                    for (int e = 0; e < KNN; ++e) {   // constant-index bubble insert
                        bool lt = (cd < Ld[m][e]) || (cd == Ld[m][e] && cc2 < Li[m][e]);
                        float td = Ld[m][e]; int ti = Li[m][e];
                        if (lt) { Ld[m][e] = cd; Li[m][e] = cc2; cd = td; cc2 = ti; }
                    }
                }
            }
        }
    }

    // merge the 16 partial lists per row through LDS
    __syncthreads();
#pragma unroll
    for (int m = 0; m < 4; ++m)
#pragma unroll
        for (int e = 0; e < KNN; ++e) {
            sh.mg.md[ty * 4 + m][tx][e] = Ld[m][e];
            sh.mg.mi[ty * 4 + m][tx][e] = Li[m][e];
        }
    __syncthreads();

    if (tid < QT) {  // wave 0: one lane per query row
        const int r = tid;
        const int q = qbase + r;
        float Bd[KNN]; int Bi[KNN];
#pragma unroll
        for (int e = 0; e < KNN; ++e) { Bd[e] = 3.0e38f; Bi[e] = 0x7fffffff; }
        for (int t = 0; t < 16; ++t) {
#pragma unroll
            for (int e0 = 0; e0 < KNN; ++e0) {
                float d  = sh.mg.md[r][t][e0];
                int   ci = sh.mg.mi[r][t][e0];
                if (d < Bd[KNN - 1] || (d == Bd[KNN - 1] && ci < Bi[KNN - 1])) {
                    float cd = d; int cc2 = ci;
#pragma unroll
                    for (int e = 0; e < KNN; ++e) {
                        bool lt = (cd < Bd[e]) || (cd == Bd[e] && cc2 < Bi[e]);
                        float td = Bd[e]; int ti = Bi[e];
                        if (lt) { Bd[e] = cd; Bi[e] = cc2; cd = td; cc2 = ti; }
                    }
                }
            }
        }
        int lq = labels[q];
        bool match = false;
#pragma unroll
        for (int j = 0; j < KNN; ++j) match = match || (labels[Bi[j]] == lq);
        unsigned long long bal = __ballot(match);
        if (tid == 0) atomicAdd(cnt, (int)__popcll(bal));
    }
}

// Kernel 3: scalar output = count / N   (power-of-two divide, exact)
__global__ void finalize_kernel(const int* __restrict__ cnt, float* __restrict__ out) {
    if (threadIdx.x == 0) out[0] = (float)(*cnt) * (1.0f / (float)NPTS);
}

extern "C" void kernel_launch(void* const* d_in, const int* in_sizes, int n_in,
                              void* d_out, int out_size, void* d_ws, size_t ws_size,
                              hipStream_t stream) {
    (void)in_sizes; (void)n_in; (void)out_size; (void)ws_size;
    const float* emb    = (const float*)d_in[0];
    const int*   labels = (const int*)d_in[1];
    float*       out    = (float*)d_out;

    int*   cnt   = (int*)d_ws;             // 4 B counter
    float* norms = (float*)d_ws + 64;      // 16384 floats at +256 B

    norms_init_kernel<<<NPTS / 4, 256, 0, stream>>>(emb, norms, cnt);
    cmc_topk_kernel<<<NPTS / QT, 256, 0, stream>>>(emb, labels, norms, cnt);
    finalize_kernel<<<1, 64, 0, stream>>>(cnt, out);
}

// Round 3
// 2896.297 us; speedup vs baseline: 1.8814x; 1.8814x over previous
//
#include <hip/hip_runtime.h>

#define NPTS 16384
#define DIM 256
#define KNN 5
#define QT 32          // query rows per block
#define CT 256         // candidate tile width
#define BK 32          // k-chunk per stage (floats) = 128 B/row
#define NKB (DIM / BK) // 8

// Kernel 1: per-row squared norms + zero the match counter.
__global__ __launch_bounds__(256) void norms_init_kernel(const float* __restrict__ emb,
                                                         float* __restrict__ norms,
                                                         int* __restrict__ cnt) {
    if (blockIdx.x == 0 && threadIdx.x == 0) *cnt = 0;
    int row  = blockIdx.x * 4 + (threadIdx.x >> 6);
    int lane = threadIdx.x & 63;
    float4 v = *reinterpret_cast<const float4*>(emb + (size_t)row * DIM + lane * 4);
    float s = v.x * v.x + v.y * v.y + v.z * v.z + v.w * v.w;
#pragma unroll
    for (int off = 32; off > 0; off >>= 1) s += __shfl_down(s, off, 64);
    if (lane == 0) norms[row] = s;
}

// Kernel 2: fused distance GEMM + per-row top-5 (self excluded) + label match count.
// A: full-K in LDS, row-major, 16B-chunk XOR swizzle slot = chunk ^ (row&7).
// B: per-stage via global_load_lds(16B), linear LDS dest + inverse-swizzled
//    global source, so reads use the same slot = chunk ^ (row&7) swizzle.
__global__ __launch_bounds__(256, 2) void cmc_topk_kernel(const float* __restrict__ emb,
                                                          const int* __restrict__ labels,
                                                          const float* __restrict__ norms,
                                                          int* __restrict__ cnt) {
    __shared__ float As[QT * DIM];   // 32 KB
    __shared__ float Bs[CT * BK];    // 32 KB
    const int tid = threadIdx.x;
    const int tx  = tid & 31;        // candidate lane group
    const int ty  = tid >> 5;        // 0..7, owns rows ty*4 .. ty*4+3
    const int qbase = blockIdx.x * QT;
    const int q0 = qbase + ty * 4;

    // ---- stage A once (full K), swizzled b128 writes (bank-balanced) ----
    {
        const int r = tid >> 3;      // 0..31 row
        const int j = tid & 7;       // 0..7
        const float* src = emb + (size_t)(qbase + r) * DIM + j * 32;
        float* dstrow = As + r * DIM;
#pragma unroll
        for (int cc = 0; cc < 8; ++cc) {
            int c = j * 8 + cc;      // 16B-chunk index 0..63
            float4 v = *reinterpret_cast<const float4*>(src + cc * 4);
            *reinterpret_cast<float4*>(dstrow + ((c ^ (r & 7)) << 2)) = v;
        }
    }

    float sqA[4];
#pragma unroll
    for (int m = 0; m < 4; ++m) sqA[m] = norms[q0 + m];

    // per-thread top-5 (dist, idx) lexicographic ascending, 4 rows
    float Ld[4][KNN];
    int   Li[4][KNN];
#pragma unroll
    for (int m = 0; m < 4; ++m)
#pragma unroll
        for (int e = 0; e < KNN; ++e) { Ld[m][e] = 3.0e38f; Li[m][e] = 0x7fffffff; }

    const int wv = tid >> 6;   // wave 0..3
    const int l  = tid & 63;   // lane

    for (int cb = 0; cb < NPTS; cb += CT) {
        float acc[4][8];
#pragma unroll
        for (int m = 0; m < 4; ++m)
#pragma unroll
            for (int n = 0; n < 8; ++n) acc[m][n] = 0.0f;

        for (int kb = 0; kb < NKB; ++kb) {
            __syncthreads();  // prev stage consumed (and A-writes visible, 1st pass)
            // stage B: 8 regions/wave, 1 KB each, direct global->LDS
#pragma unroll
            for (int c = 0; c < 8; ++c) {
                int R   = wv * 8 + c;                 // region 0..31 (8 Bs rows)
                int row = R * 8 + (l >> 3);           // candidate row in tile
                int kv  = (l & 7) ^ ((l >> 3) & 7);   // inverse-swizzled chunk
                const float* g = emb + (size_t)(cb + row) * DIM + kb * BK + kv * 4;
                __builtin_amdgcn_global_load_lds(
                    (const __attribute__((address_space(1))) void*)g,
                    (__attribute__((address_space(3))) void*)(Bs + R * 256),
                    16, 0, 0);
            }
            __syncthreads();  // drain (compiler emits vmcnt(0) before barrier)

            // compute: 8 k4-groups x (4 rows x 8 cands x 4 k) FMAs
            for (int k4 = 0; k4 < 8; ++k4) {
                float4 a4[4], b4[8];
#pragma unroll
                for (int m = 0; m < 4; ++m) {
                    int row = ty * 4 + m;
                    a4[m] = *reinterpret_cast<const float4*>(
                        As + row * DIM + ((kb * 8 + (k4 ^ (row & 7))) << 2));
                }
#pragma unroll
                for (int n = 0; n < 8; ++n)
                    b4[n] = *reinterpret_cast<const float4*>(
                        Bs + (tx + 32 * n) * BK + ((k4 ^ (tx & 7)) << 2));
#pragma unroll
                for (int m = 0; m < 4; ++m)
#pragma unroll
                    for (int n = 0; n < 8; ++n) {   // ascending k, fp32 fma chain
                        acc[m][n] = fmaf(a4[m].x, b4[n].x, acc[m][n]);
                        acc[m][n] = fmaf(a4[m].y, b4[n].y, acc[m][n]);
                        acc[m][n] = fmaf(a4[m].z, b4[n].z, acc[m][n]);
                        acc[m][n] = fmaf(a4[m].w, b4[n].w, acc[m][n]);
                    }
            }
        }

        // epilogue: finalize distances, update top-5 lists
#pragma unroll
        for (int n = 0; n < 8; ++n) {
            int ci = cb + tx + 32 * n;
            float sqB = norms[ci];
#pragma unroll
            for (int m = 0; m < 4; ++m) {
                float dist = fmaf(-2.0f, acc[m][n], sqA[m] + sqB);
                if (ci != q0 + m && (dist < Ld[m][KNN - 1] ||
                                     (dist == Ld[m][KNN - 1] && ci < Li[m][KNN - 1]))) {
                    float cd = dist; int cc2 = ci;
#pragma unroll
                    for (int e = 0; e < KNN; ++e) {  // constant-index bubble insert
                        bool lt = (cd < Ld[m][e]) || (cd == Ld[m][e] && cc2 < Li[m][e]);
                        float td = Ld[m][e]; int ti = Li[m][e];
                        if (lt) { Ld[m][e] = cd; Li[m][e] = cc2; cd = td; cc2 = ti; }
                    }
                }
            }
        }
    }

    // ---- butterfly merge across tx with SNAPSHOT semantics (bug fix) ----
    // All 5 partner pairs are shuffled into temporaries BEFORE any insertion,
    // so each round merges static pre-round lists (groups are disjoint -> no dups).
#pragma unroll
    for (int mask = 1; mask <= 16; mask <<= 1) {
#pragma unroll
        for (int m = 0; m < 4; ++m) {
            float pd[KNN]; int pi[KNN];
#pragma unroll
            for (int e = 0; e < KNN; ++e) {
                pd[e] = __shfl_xor(Ld[m][e], mask, 64);
                pi[e] = __shfl_xor(Li[m][e], mask, 64);
            }
#pragma unroll
            for (int e0 = 0; e0 < KNN; ++e0) {
                float cd = pd[e0]; int cc2 = pi[e0];
                if (cd < Ld[m][KNN - 1] ||
                    (cd == Ld[m][KNN - 1] && cc2 < Li[m][KNN - 1])) {
#pragma unroll
                    for (int e = 0; e < KNN; ++e) {
                        bool lt = (cd < Ld[m][e]) || (cd == Ld[m][e] && cc2 < Li[m][e]);
                        float td = Ld[m][e]; int ti = Li[m][e];
                        if (lt) { Ld[m][e] = cd; Li[m][e] = cc2; cd = td; cc2 = ti; }
                    }
                }
            }
        }
    }

    if (tx == 0) {  // one leader per 4-row group
        int local = 0;
#pragma unroll
        for (int m = 0; m < 4; ++m) {
            int lq = labels[q0 + m];
            bool match = false;
#pragma unroll
            for (int e = 0; e < KNN; ++e) match = match || (labels[Li[m][e]] == lq);
            local += match ? 1 : 0;
        }
        atomicAdd(cnt, local);
    }
}

// Kernel 3: scalar output = count / N (power-of-two divide, exact)
__global__ void finalize_kernel(const int* __restrict__ cnt, float* __restrict__ out) {
    if (threadIdx.x == 0) out[0] = (float)(*cnt) * (1.0f / (float)NPTS);
}

extern "C" void kernel_launch(void* const* d_in, const int* in_sizes, int n_in,
                              void* d_out, int out_size, void* d_ws, size_t ws_size,
                              hipStream_t stream) {
    (void)in_sizes; (void)n_in; (void)out_size; (void)ws_size;
    const float* emb    = (const float*)d_in[0];
    const int*   labels = (const int*)d_in[1];
    float*       out    = (float*)d_out;

    int*   cnt   = (int*)d_ws;            // 4 B counter
    float* norms = (float*)d_ws + 64;     // 16384 floats at +256 B

    norms_init_kernel<<<NPTS / 4, 256, 0, stream>>>(emb, norms, cnt);
    cmc_topk_kernel<<<NPTS / QT, 256, 0, stream>>>(emb, labels, norms, cnt);
    finalize_kernel<<<1, 64, 0, stream>>>(cnt, out);
}

// Round 4
// 1341.018 us; speedup vs baseline: 4.0635x; 2.1598x over previous
//
#include <hip/hip_runtime.h>

#define NPTS 16384
#define DIM 256
#define KNN 5
#define RPB 64                    // query rows per block (panel)
#define STRIPS 4
#define STRIP (NPTS / STRIPS)     // 4096 candidates per strip
#define CTILE 256                 // candidates per tile
#define NCB (STRIP / CTILE)       // 16
#define TOPS 8                    // per-strip shortlist depth

typedef _Float16 f16x8 __attribute__((ext_vector_type(8)));
typedef float    f32x4 __attribute__((ext_vector_type(4)));

// workspace byte offsets
#define WS_CNT   0
#define WS_NORMS 4096
#define WS_HI    131072
#define WS_SL    (WS_HI + NPTS * DIM * 2)   // int shortlist [NPTS][32]

// lexicographic (score, idx) ascending bubble insert, constant indices only
#define INSERT8(Ls, Li, sc, ix) do {                                          \
    if ((sc) < (Ls)[TOPS-1] || ((sc) == (Ls)[TOPS-1] && (ix) < (Li)[TOPS-1])) { \
        float _d = (sc); int _i = (ix);                                       \
        _Pragma("unroll")                                                     \
        for (int _e = 0; _e < TOPS; ++_e) {                                   \
            bool _lt = (_d < (Ls)[_e]) || (_d == (Ls)[_e] && _i < (Li)[_e]);  \
            float _td = (Ls)[_e]; int _ti = (Li)[_e];                         \
            if (_lt) { (Ls)[_e] = _d; (Li)[_e] = _i; _d = _td; _i = _ti; }    \
        }                                                                     \
    } } while (0)

// K0: per-row squared norms (fp32) + fp16 copy of embeddings + zero counter.
__global__ __launch_bounds__(256) void prep_kernel(const float* __restrict__ emb,
                                                   float* __restrict__ norms,
                                                   _Float16* __restrict__ hi,
                                                   int* __restrict__ cnt) {
    if (blockIdx.x == 0 && threadIdx.x == 0) *cnt = 0;
    int row = blockIdx.x * 4 + (threadIdx.x >> 6);
    int l   = threadIdx.x & 63;
    float4 v = *reinterpret_cast<const float4*>(emb + (size_t)row * DIM + l * 4);
    union { _Float16 h[4]; short4 s; } u;
    u.h[0] = (_Float16)v.x; u.h[1] = (_Float16)v.y;
    u.h[2] = (_Float16)v.z; u.h[3] = (_Float16)v.w;
    *reinterpret_cast<short4*>(hi + (size_t)row * DIM + l * 4) = u.s;
    float s = v.x * v.x + v.y * v.y + v.z * v.z + v.w * v.w;
#pragma unroll
    for (int off = 32; off > 0; off >>= 1) s += __shfl_down(s, off, 64);
    if (l == 0) norms[row] = s;
}

// K1: fp16 MFMA filter. Block = 64 query rows x one 4096-cand strip.
// Swapped operands: D[m=cand][n=row] = mfma(A=cand_tile, B=row_panel).
// Each lane owns 4 rows' top-8 (score = ||b||^2 - 2 a.b) lists.
struct StageS {
    alignas(16) _Float16 Bt[RPB * DIM];     // 32 KB row panel, full K, swizzled
    alignas(16) _Float16 At[CTILE * 64];    // 32 KB cand tile, 64-k window, swizzled
    alignas(16) float    nC[CTILE];         // candidate norms
};
struct MergeS {
    alignas(16) float mgS[3][RPB][TOPS];
    alignas(16) int   mgI[3][RPB][TOPS];
};
union SMem { StageS st; MergeS mg; };

__global__ __launch_bounds__(256, 2) void filter_kernel(const _Float16* __restrict__ hi,
                                                        const float* __restrict__ norms,
                                                        int* __restrict__ shortlist) {
    __shared__ SMem sm;
    const int tid = threadIdx.x;
    const int w = tid >> 6;          // wave 0..3 (cand quarter)
    const int l = tid & 63;
    const int panel = blockIdx.x >> 2;
    const int strip = blockIdx.x & 3;            // XCD x serves strip x&3 (L2 affinity)
    const int qbase = panel * RPB;
    const int cand0 = strip * STRIP;

    // ---- stage B row-panel once: linear LDS dest, inverse-swizzled source ----
#pragma unroll
    for (int i = 0; i < 8; ++i) {
        int off = (w * 8 + i) * 1024 + l * 16;     // linear byte in Bt
        int row = off >> 9;                        // 512 B rows
        int s   = (off >> 4) & 31;                 // 16B slot
        int c   = s ^ (row & 7);                   // source chunk
        const _Float16* g = hi + (size_t)(qbase + row) * DIM + c * 8;
        __builtin_amdgcn_global_load_lds(
            (const __attribute__((address_space(1))) void*)g,
            (__attribute__((address_space(3))) void*)((char*)sm.st.Bt + (w * 8 + i) * 1024),
            16, 0, 0);
    }

    float Ls[4][TOPS]; int Li_[4][TOPS];
#pragma unroll
    for (int rf = 0; rf < 4; ++rf)
#pragma unroll
        for (int e = 0; e < TOPS; ++e) { Ls[rf][e] = 3.0e38f; Li_[rf][e] = 0x7fffffff; }

    for (int cb = 0; cb < NCB; ++cb) {
        const int cbase = cand0 + cb * CTILE;
        f32x4 acc[4][4];
#pragma unroll
        for (int cf = 0; cf < 4; ++cf)
#pragma unroll
            for (int rf = 0; rf < 4; ++rf) acc[cf][rf] = (f32x4){0.f, 0.f, 0.f, 0.f};

        for (int kb = 0; kb < 4; ++kb) {
            __syncthreads();   // prev A window consumed (also covers B on 1st pass)
#pragma unroll
            for (int i = 0; i < 8; ++i) {
                int off  = (w * 8 + i) * 1024 + l * 16;
                int crow = off >> 7;               // 128 B rows
                int s    = (off >> 4) & 7;
                int c    = s ^ (crow & 7);
                const _Float16* g = hi + (size_t)(cbase + crow) * DIM + kb * 64 + c * 8;
                __builtin_amdgcn_global_load_lds(
                    (const __attribute__((address_space(1))) void*)g,
                    (__attribute__((address_space(3))) void*)((char*)sm.st.At + (w * 8 + i) * 1024),
                    16, 0, 0);
            }
            if (kb == 0 && w == 0) {               // candidate norms, 1 KB linear
                const float* g = norms + cbase + l * 4;
                __builtin_amdgcn_global_load_lds(
                    (const __attribute__((address_space(1))) void*)g,
                    (__attribute__((address_space(3))) void*)sm.st.nC, 16, 0, 0);
            }
            __syncthreads();   // vmcnt(0) drain before use

#pragma unroll
            for (int ks = 0; ks < 2; ++ks) {
                const int vk = kb * 2 + ks;
                f16x8 af[4], bf[4];
#pragma unroll
                for (int cf = 0; cf < 4; ++cf) {
                    int crow  = w * 64 + cf * 16 + (l & 15);
                    int chunk = ks * 4 + (l >> 4);
                    int slot  = chunk ^ (crow & 7);
                    af[cf] = *reinterpret_cast<const f16x8*>(
                        (const char*)sm.st.At + crow * 128 + slot * 16);
                }
#pragma unroll
                for (int rf = 0; rf < 4; ++rf) {
                    int rrow  = rf * 16 + (l & 15);
                    int chunk = vk * 4 + (l >> 4);
                    int slot  = chunk ^ (rrow & 7);
                    bf[rf] = *reinterpret_cast<const f16x8*>(
                        (const char*)sm.st.Bt + rrow * 512 + slot * 16);
                }
#pragma unroll
                for (int cf = 0; cf < 4; ++cf)
#pragma unroll
                    for (int rf = 0; rf < 4; ++rf)
                        acc[cf][rf] = __builtin_amdgcn_mfma_f32_16x16x32_f16(
                            af[cf], bf[rf], acc[cf][rf], 0, 0, 0);
            }
        }

        // epilogue: score = sqB - 2*dot; update per-row top-8
#pragma unroll
        for (int cf = 0; cf < 4; ++cf) {
            f32x4 nb = *reinterpret_cast<const f32x4*>(
                sm.st.nC + w * 64 + cf * 16 + (l >> 4) * 4);
            int cglob0 = cbase + w * 64 + cf * 16 + (l >> 4) * 4;
#pragma unroll
            for (int rf = 0; rf < 4; ++rf) {
#pragma unroll
                for (int r = 0; r < 4; ++r) {
                    float score = fmaf(-2.0f, acc[cf][rf][r], nb[r]);
                    int ci = cglob0 + r;
                    INSERT8(Ls[rf], Li_[rf], score, ci);
                }
            }
        }
    }

    // ---- in-wave butterfly merge across cand groups (snapshot semantics) ----
#pragma unroll
    for (int mask = 16; mask <= 32; mask <<= 1) {
#pragma unroll
        for (int rf = 0; rf < 4; ++rf) {
            float pd[TOPS]; int pi[TOPS];
#pragma unroll
            for (int e = 0; e < TOPS; ++e) {
                pd[e] = __shfl_xor(Ls[rf][e], mask, 64);
                pi[e] = __shfl_xor(Li_[rf][e], mask, 64);
            }
#pragma unroll
            for (int e = 0; e < TOPS; ++e) INSERT8(Ls[rf], Li_[rf], pd[e], pi[e]);
        }
    }

    // ---- cross-wave merge via LDS (waves 1-3 publish, wave 0 merges+writes) ----
    __syncthreads();             // stage buffers dead; reuse as merge scratch
    if (w > 0 && (l >> 4) == 0) {
#pragma unroll
        for (int rf = 0; rf < 4; ++rf) {
            int row = rf * 16 + l;
#pragma unroll
            for (int e = 0; e < TOPS; ++e) {
                sm.mg.mgS[w - 1][row][e] = Ls[rf][e];
                sm.mg.mgI[w - 1][row][e] = Li_[rf][e];
            }
        }
    }
    __syncthreads();
    if (w == 0 && (l >> 4) == 0) {
#pragma unroll
        for (int rf = 0; rf < 4; ++rf) {
            int row = rf * 16 + l;
            for (int t = 0; t < 3; ++t)
#pragma unroll
                for (int e = 0; e < TOPS; ++e)
                    INSERT8(Ls[rf], Li_[rf], sm.mg.mgS[t][row][e], sm.mg.mgI[t][row][e]);
            int* dst = shortlist + (size_t)(qbase + row) * 32 + strip * 8;
            int4 w0 = make_int4(Li_[rf][0], Li_[rf][1], Li_[rf][2], Li_[rf][3]);
            int4 w1 = make_int4(Li_[rf][4], Li_[rf][5], Li_[rf][6], Li_[rf][7]);
            *reinterpret_cast<int4*>(dst)     = w0;
            *reinterpret_cast<int4*>(dst + 4) = w1;
        }
    }
}

// K2: exact fp32 rescore of the 32 shortlisted candidates per row; top-5 by
// (dist, idx) lexicographic; label match; atomic count. One wave per row.
__global__ __launch_bounds__(256) void rescore_kernel(const float* __restrict__ emb,
                                                      const int* __restrict__ labels,
                                                      const float* __restrict__ norms,
                                                      const int* __restrict__ shortlist,
                                                      int* __restrict__ cnt) {
    __shared__ float qrow[4][DIM];
    const int tid = threadIdx.x;
    const int w = tid >> 6;
    const int l = tid & 63;
    const int q = blockIdx.x * 4 + w;

    float4 qv = *reinterpret_cast<const float4*>(emb + (size_t)q * DIM + l * 4);
    *reinterpret_cast<float4*>(&qrow[w][l * 4]) = qv;
    __syncthreads();

    float dloc = 3.0e38f; int iloc = 0x7fffffff;
    if (l < 32) {
        int ci = shortlist[(size_t)q * 32 + l];
        if (ci != q) {
            const float* crow = emb + (size_t)ci * DIM;
            float p0 = 0.f, p1 = 0.f, p2 = 0.f, p3 = 0.f;
#pragma unroll 8
            for (int kk = 0; kk < 64; ++kk) {
                float4 c4 = *reinterpret_cast<const float4*>(crow + kk * 4);
                float4 q4 = *reinterpret_cast<const float4*>(&qrow[w][kk * 4]);
                p0 = fmaf(c4.x, q4.x, p0);
                p1 = fmaf(c4.y, q4.y, p1);
                p2 = fmaf(c4.z, q4.z, p2);
                p3 = fmaf(c4.w, q4.w, p3);
            }
            float dot = (p0 + p1) + (p2 + p3);
            dloc = fmaf(-2.0f, dot, norms[q] + norms[ci]);
            iloc = ci;
        }
    }

    const int lq = labels[q];
    bool match = false;
#pragma unroll
    for (int r = 0; r < KNN; ++r) {
        float md = dloc; int mi = iloc;
#pragma unroll
        for (int mask = 1; mask <= 32; mask <<= 1) {
            float pd = __shfl_xor(md, mask, 64);
            int   pi = __shfl_xor(mi, mask, 64);
            if (pd < md || (pd == md && pi < mi)) { md = pd; mi = pi; }
        }
        if (iloc == mi) dloc = 3.0e38f;   // owner retires its candidate
        match = match || (labels[mi] == lq);
    }
    if (l == 0) atomicAdd(cnt, match ? 1 : 0);
}

// K3: scalar output = count / N (power-of-two divide, exact)
__global__ void finalize_kernel(const int* __restrict__ cnt, float* __restrict__ out) {
    if (threadIdx.x == 0) out[0] = (float)(*cnt) * (1.0f / (float)NPTS);
}

extern "C" void kernel_launch(void* const* d_in, const int* in_sizes, int n_in,
                              void* d_out, int out_size, void* d_ws, size_t ws_size,
                              hipStream_t stream) {
    (void)in_sizes; (void)n_in; (void)out_size; (void)ws_size;
    const float* emb    = (const float*)d_in[0];
    const int*   labels = (const int*)d_in[1];
    float*       out    = (float*)d_out;

    char* ws = (char*)d_ws;
    int*      cnt       = (int*)(ws + WS_CNT);
    float*    norms     = (float*)(ws + WS_NORMS);
    _Float16* hi        = (_Float16*)(ws + WS_HI);
    int*      shortlist = (int*)(ws + WS_SL);

    prep_kernel<<<NPTS / 4, 256, 0, stream>>>(emb, norms, hi, cnt);
    filter_kernel<<<(NPTS / RPB) * STRIPS, 256, 0, stream>>>(hi, norms, shortlist);
    rescore_kernel<<<NPTS / 4, 256, 0, stream>>>(emb, labels, norms, shortlist, cnt);
    finalize_kernel<<<1, 64, 0, stream>>>(cnt, out);
}